// Round 8
// baseline (179.441 us; speedup 1.0000x reference)
//
#include <hip/hip_runtime.h>

#define BATCH 8192
#define LOSC  2048.0f
#define LOINV (1.0f / 2048.0f)

typedef _Float16 f16x4 __attribute__((ext_vector_type(4)));
typedef __fp16   fp16x2 __attribute__((ext_vector_type(2)));
typedef float    f32x4 __attribute__((ext_vector_type(4)));

union PK2 { fp16x2 h; unsigned u; };
union U4  { f16x4 v; unsigned u[2]; };

__device__ __forceinline__ unsigned pkrtz(float a, float b) {
    PK2 p; p.h = __builtin_amdgcn_cvt_pkrtz(a, b); return p.u;
}
__device__ __forceinline__ float lo0(unsigned hp, float v) {
    PK2 p; p.u = hp; return (v - (float)p.h[0]) * LOSC;
}
__device__ __forceinline__ float lo1(unsigned hp, float v) {
    PK2 p; p.u = hp; return (v - (float)p.h[1]) * LOSC;
}

// ---------------------------------------------------------------------------
// Fused kernel (v8): NN + 50-step solver in ONE kernel, 1024 blocks x 1 wave.
//
// NN phase: block stages c (32 KB) in LDS; 8 lanes per sample scan 2048
// float4s (partition p = lane&7 -> same-address broadcast across groups,
// disjoint banks across p: conflict-free). Exact reference semantics:
// sqrt(fl(dx*dx)) == |dx| in fp32, first-index argmin via strict < over
// ascending index + lexicographic (d, idx) merges, self excluded.
//
// Solver: 8 samples/wave, B cols = [8 fwd | 8 tangent]. Split-f16 via
// mfma_f32_16x16x16_f16 (K=16): B k-map (q*4+j) == C/D row map (q*4+r), so
// C-tile T is B-chunk T per-lane — zero-shfl inter-layer transform. All
// weights (hi+lo) in registers; no in-loop LDS. Mask shfls batched.
// ---------------------------------------------------------------------------
__global__ __launch_bounds__(64, 1) void solve_kernel(
    const float* __restrict__ x, const float* __restrict__ c,
    const float* __restrict__ W1, const float* __restrict__ b1,
    const float* __restrict__ W2, const float* __restrict__ b2,
    const float* __restrict__ W3, const float* __restrict__ b3,
    const float* __restrict__ W4, float* __restrict__ out)
{
    __shared__ float cs[BATCH];           // 32 KB

    const int lane = threadIdx.x & 63;
    const int q  = lane >> 4;
    const int cc = lane & 15;
    const bool fwd = (cc < 8);
    const int s = cc & 7;
    const int sbase = blockIdx.x * 8;

    // ================= NN phase =================
    {
        const float4* cg = (const float4*)c;
        float4* cl = (float4*)cs;
        #pragma unroll 4
        for (int w = lane; w < BATCH / 4; w += 64) cl[w] = cg[w];
    }
    __syncthreads();   // single wave: compiles to waitcnt+barrier, one-time

    float c0s;
    {
        const int il = lane >> 3;          // this group's sample 0..7
        const int p  = lane & 7;           // partition within group
        const int ni = sbase + il;         // global sample index
        const float ci = cs[ni];
        const int iw = ni >> 2;            // self float4 index
        const int sj0 = (((iw & 7) == p) && ((ni & 3) == 0)) ? iw : -1;
        const int sj1 = (((iw & 7) == p) && ((ni & 3) == 1)) ? iw : -1;
        const int sj2 = (((iw & 7) == p) && ((ni & 3) == 2)) ? iw : -1;
        const int sj3 = (((iw & 7) == p) && ((ni & 3) == 3)) ? iw : -1;
        const float4* cs4 = (const float4*)cs;
        float bd0 = 3e38f, bd1 = 3e38f, bd2 = 3e38f, bd3 = 3e38f;
        int   bj0 = 0,     bj1 = 0,     bj2 = 0,     bj3 = 0;
        #pragma unroll 4
        for (int t = 0; t < 256; ++t) {
            const int jj = p + (t << 3);
            const float4 v = cs4[jj];
            float d0 = fabsf(ci - v.x);
            float d1 = fabsf(ci - v.y);
            float d2 = fabsf(ci - v.z);
            float d3 = fabsf(ci - v.w);
            if (jj == sj0) d0 = 3e38f;
            if (jj == sj1) d1 = 3e38f;
            if (jj == sj2) d2 = 3e38f;
            if (jj == sj3) d3 = 3e38f;
            if (d0 < bd0) { bd0 = d0; bj0 = jj; }   // strict < + ascending jj
            if (d1 < bd1) { bd1 = d1; bj1 = jj; }
            if (d2 < bd2) { bd2 = d2; bj2 = jj; }
            if (d3 < bd3) { bd3 = d3; bj3 = jj; }
        }
        float best = bd0; int bestj = bj0 * 4 + 0;
        { const int j1 = bj1 * 4 + 1; if (bd1 < best || (bd1 == best && j1 < bestj)) { best = bd1; bestj = j1; } }
        { const int j2 = bj2 * 4 + 2; if (bd2 < best || (bd2 == best && j2 < bestj)) { best = bd2; bestj = j2; } }
        { const int j3 = bj3 * 4 + 3; if (bd3 < best || (bd3 == best && j3 < bestj)) { best = bd3; bestj = j3; } }
        #pragma unroll
        for (int off = 1; off < 8; off <<= 1) {     // merge the 8 partitions
            const float od = __shfl_xor(best, off);
            const int   oj = __shfl_xor(bestj, off);
            if (od < best || (od == best && oj < bestj)) { best = od; bestj = oj; }
        }
        const float c0grp = cs[bestj];     // all 8 lanes of group agree
        c0s = __shfl(c0grp, s * 8);        // fetch own sample's c0
    }

    // ================= weight staging (registers) =================
    // A-frag (T,m): lane holds W[(T*16+cc)][m*16 + q*4 + j], j=0..3
    f16x4 W2h[4][4], W2l[4][4], W3h[4][4], W3l[4][4];
    #pragma unroll
    for (int T = 0; T < 4; ++T)
        #pragma unroll
        for (int m = 0; m < 4; ++m) {
            const int off = (T * 16 + cc) * 64 + m * 16 + q * 4;
            const float4 w2 = *(const float4*)(W2 + off);
            const float4 w3 = *(const float4*)(W3 + off);
            U4 h, l;
            h.u[0] = pkrtz(w2.x, w2.y); h.u[1] = pkrtz(w2.z, w2.w);
            l.u[0] = pkrtz(lo0(h.u[0], w2.x), lo1(h.u[0], w2.y));
            l.u[1] = pkrtz(lo0(h.u[1], w2.z), lo1(h.u[1], w2.w));
            W2h[T][m] = h.v; W2l[T][m] = l.v;
            h.u[0] = pkrtz(w3.x, w3.y); h.u[1] = pkrtz(w3.z, w3.w);
            l.u[0] = pkrtz(lo0(h.u[0], w3.x), lo1(h.u[0], w3.y));
            l.u[1] = pkrtz(lo0(h.u[1], w3.z), lo1(h.u[1], w3.w));
            W3h[T][m] = h.v; W3l[T][m] = l.v;
        }

    float b2m[16], b3m[16], w4r[16];
    #pragma unroll
    for (int T = 0; T < 4; ++T)
        #pragma unroll
        for (int r = 0; r < 4; ++r) {
            const int row = T * 16 + q * 4 + r;
            b2m[T * 4 + r] = fwd ? b2[row] : 0.f;
            b3m[T * 4 + r] = fwd ? b3[row] : 0.f;
            w4r[T * 4 + r] = W4[row];
        }

    float A1v[16], w11v[16];
    {
        const float xs = x[sbase + s];
        #pragma unroll
        for (int m = 0; m < 4; ++m)
            #pragma unroll
            for (int j = 0; j < 4; ++j) {
                const int k = m * 16 + q * 4 + j;
                w11v[m * 4 + j] = W1[k * 3 + 1];
                A1v[m * 4 + j]  = fmaf(xs, W1[k * 3 + 0],
                                       fmaf(c0s, W1[k * 3 + 2], b1[k]));
            }
    }

    // ================= 50-step solver =================
    float y = 0.0f;

    #pragma unroll 1
    for (int step = 0; step < 50; ++step) {
        // ---- layer 1 (fp32, registers) -> split B1 chunks ----
        U4 B1h[4], B1l[4];
        #pragma unroll
        for (int m = 0; m < 4; ++m) {
            float v[4];
            #pragma unroll
            for (int j = 0; j < 4; ++j) {
                const float w = w11v[m * 4 + j];
                const float z = fmaf(y, w, A1v[m * 4 + j]);
                v[j] = fwd ? fmaxf(z, 0.f) : (z > 0.f ? w : 0.f);
            }
            const unsigned h0 = pkrtz(v[0], v[1]);
            const unsigned h1 = pkrtz(v[2], v[3]);
            B1h[m].u[0] = h0; B1h[m].u[1] = h1;
            B1l[m].u[0] = pkrtz(lo0(h0, v[0]), lo1(h0, v[1]));
            B1l[m].u[1] = pkrtz(lo0(h1, v[2]), lo1(h1, v[3]));
        }
        // ---- layer 2: split MFMA (K=16 x 4 chunks) ----
        f32x4 ZH[4], ZL[4];
        #pragma unroll
        for (int T = 0; T < 4; ++T) {
            f32x4 aH;
            aH[0] = b2m[T * 4 + 0]; aH[1] = b2m[T * 4 + 1];
            aH[2] = b2m[T * 4 + 2]; aH[3] = b2m[T * 4 + 3];
            f32x4 aL = {0.f, 0.f, 0.f, 0.f};
            #pragma unroll
            for (int m = 0; m < 4; ++m) {
                aH = __builtin_amdgcn_mfma_f32_16x16x16f16(W2h[T][m], B1h[m].v, aH, 0, 0, 0);
                aL = __builtin_amdgcn_mfma_f32_16x16x16f16(W2h[T][m], B1l[m].v, aL, 0, 0, 0);
                aL = __builtin_amdgcn_mfma_f32_16x16x16f16(W2l[T][m], B1h[m].v, aL, 0, 0, 0);
            }
            ZH[T] = aH; ZL[T] = aL;
        }
        // ---- combine; batch ALL mask shfls; then select + split ----
        float z2[16], rc2[16];
        #pragma unroll
        for (int k = 0; k < 16; ++k)
            z2[k] = fmaf(ZL[k >> 2][k & 3], LOINV, ZH[k >> 2][k & 3]);
        #pragma unroll
        for (int k = 0; k < 16; ++k)
            rc2[k] = __shfl_xor(z2[k], 8);
        U4 B2h[4], B2l[4];
        #pragma unroll
        for (int T = 0; T < 4; ++T) {
            float v[4];
            #pragma unroll
            for (int r = 0; r < 4; ++r) {
                const float z = z2[T * 4 + r];
                v[r] = fwd ? fmaxf(z, 0.f) : (rc2[T * 4 + r] > 0.f ? z : 0.f);
            }
            const unsigned h0 = pkrtz(v[0], v[1]);
            const unsigned h1 = pkrtz(v[2], v[3]);
            B2h[T].u[0] = h0; B2h[T].u[1] = h1;
            B2l[T].u[0] = pkrtz(lo0(h0, v[0]), lo1(h0, v[1]));
            B2l[T].u[1] = pkrtz(lo0(h1, v[2]), lo1(h1, v[3]));
        }
        // ---- layer 3: split MFMA ----
        #pragma unroll
        for (int T = 0; T < 4; ++T) {
            f32x4 aH;
            aH[0] = b3m[T * 4 + 0]; aH[1] = b3m[T * 4 + 1];
            aH[2] = b3m[T * 4 + 2]; aH[3] = b3m[T * 4 + 3];
            f32x4 aL = {0.f, 0.f, 0.f, 0.f};
            #pragma unroll
            for (int m = 0; m < 4; ++m) {
                aH = __builtin_amdgcn_mfma_f32_16x16x16f16(W3h[T][m], B2h[m].v, aH, 0, 0, 0);
                aL = __builtin_amdgcn_mfma_f32_16x16x16f16(W3h[T][m], B2l[m].v, aL, 0, 0, 0);
                aL = __builtin_amdgcn_mfma_f32_16x16x16f16(W3l[T][m], B2h[m].v, aL, 0, 0, 0);
            }
            ZH[T] = aH; ZL[T] = aL;
        }
        // ---- layer 4 (fp32): batch shfls, then g = W4 . (1[z3>0] * dz3) ----
        float z3[16], rc3[16];
        #pragma unroll
        for (int k = 0; k < 16; ++k)
            z3[k] = fmaf(ZL[k >> 2][k & 3], LOINV, ZH[k >> 2][k & 3]);
        #pragma unroll
        for (int k = 0; k < 16; ++k)
            rc3[k] = __shfl_xor(z3[k], 8);
        float g = 0.f;
        #pragma unroll
        for (int k = 0; k < 16; ++k) {
            const float maskv = fwd ? z3[k] : rc3[k];   // z3 fwd (with bias)
            const float valv  = fwd ? rc3[k] : z3[k];   // dz3
            g = fmaf(w4r[k], (maskv > 0.f) ? valv : 0.f, g);
        }
        g += __shfl_xor(g, 16);   // quad sums: identical per sample pair
        g += __shfl_xor(g, 32);
        y -= 0.1f * g;
    }
    if (lane < 8) out[sbase + lane] = y;
}

extern "C" void kernel_launch(void* const* d_in, const int* in_sizes, int n_in,
                              void* d_out, int out_size, void* d_ws, size_t ws_size,
                              hipStream_t stream) {
    const float* x  = (const float*)d_in[0];
    const float* c  = (const float*)d_in[1];
    const float* W1 = (const float*)d_in[2];
    const float* b1 = (const float*)d_in[3];
    const float* W2 = (const float*)d_in[4];
    const float* b2 = (const float*)d_in[5];
    const float* W3 = (const float*)d_in[6];
    const float* b3 = (const float*)d_in[7];
    const float* W4 = (const float*)d_in[8];
    // d_in[9] = b4: unused (only grad wrt y is needed, b4 drops out)
    float* out = (float*)d_out;

    solve_kernel<<<BATCH / 8, 64, 0, stream>>>(x, c, W1, b1, W2, b2, W3, b3, W4, out);
}